// Round 5
// baseline (193.831 us; speedup 1.0000x reference)
//
#include <hip/hip_runtime.h>
#include <hip/hip_bf16.h>

#define NROW 8192
#define DDIM 1024
#define TINV 2.0f   // 1 / TEMPERATURE

typedef __attribute__((ext_vector_type(16))) float f32x16;
typedef __attribute__((ext_vector_type(8))) short short8;

__device__ __forceinline__ ushort f2bf(float f) {
  union { float f; unsigned u; } x; x.f = f;
  unsigned r = x.u + 0x7fffu + ((x.u >> 16) & 1u);  // RNE
  return (ushort)(r >> 16);
}

__device__ __forceinline__ void gload_lds16(const void* g, void* l) {
  __builtin_amdgcn_global_load_lds(
      (const __attribute__((address_space(1))) void*)g,
      (__attribute__((address_space(3))) void*)l, 16, 0, 0);
}

#define SBAR()  __builtin_amdgcn_s_barrier()
#define PRIO(x) __builtin_amdgcn_s_setprio(x)
#define VMCNT(N) asm volatile("s_waitcnt vmcnt(" #N ")" ::: "memory")

// ---------------------------------------------------------------------------
// Kernel 1: per-row L2 norms, diag, bf16 normalized copies (z1 pre-scaled 1/T)
// ---------------------------------------------------------------------------
__global__ __launch_bounds__(256) void normalize_diag(
    const float* __restrict__ v1, const float* __restrict__ v2,
    ushort* __restrict__ z1, ushort* __restrict__ z2,
    float* __restrict__ diag)
{
  const int row = blockIdx.x;
  const int t = threadIdx.x;
  const float4 a = ((const float4*)(v1 + (size_t)row * DDIM))[t];
  const float4 b = ((const float4*)(v2 + (size_t)row * DDIM))[t];
  float s1 = a.x*a.x + a.y*a.y + a.z*a.z + a.w*a.w;
  float s2 = b.x*b.x + b.y*b.y + b.z*b.z + b.w*b.w;
  float sd = a.x*b.x + a.y*b.y + a.z*b.z + a.w*b.w;
  #pragma unroll
  for (int m = 1; m < 64; m <<= 1) {
    s1 += __shfl_xor(s1, m);
    s2 += __shfl_xor(s2, m);
    sd += __shfl_xor(sd, m);
  }
  __shared__ float red[3][4];
  const int w = t >> 6;
  if ((t & 63) == 0) { red[0][w] = s1; red[1][w] = s2; red[2][w] = sd; }
  __syncthreads();
  s1 = red[0][0] + red[0][1] + red[0][2] + red[0][3];
  s2 = red[1][0] + red[1][1] + red[1][2] + red[1][3];
  sd = red[2][0] + red[2][1] + red[2][2] + red[2][3];
  const float i1 = 1.0f / fmaxf(sqrtf(s1), 1e-12f);
  const float i2 = 1.0f / fmaxf(sqrtf(s2), 1e-12f);
  if (t == 0) diag[row] = sd * i1 * i2 * TINV;
  const float sc1 = i1 * TINV;
  ushort4 o1, o2;
  o1.x = f2bf(a.x * sc1); o1.y = f2bf(a.y * sc1);
  o1.z = f2bf(a.z * sc1); o1.w = f2bf(a.w * sc1);
  o2.x = f2bf(b.x * i2);  o2.y = f2bf(b.y * i2);
  o2.z = f2bf(b.z * i2);  o2.w = f2bf(b.w * i2);
  ((ushort4*)(z1 + (size_t)row * DDIM))[t] = o1;
  ((ushort4*)(z2 + (size_t)row * DDIM))[t] = o2;
}

// ---------------------------------------------------------------------------
// Kernel 2: 256x256-tile GEMM (sim = z1*z2^T) + fused exp-rowsum.
// 8 waves (2M x 4N), BK=64, 2-buffer LDS, T2 XOR-swizzle, counted vmcnt,
// T5 setprio, NO sched pinning. MFMA = 32x32x16 bf16 (2495 TF pipe, half
// the instruction count of 16x16x32 at identical LDS traffic).
// Per-wave output 128x64 = 4m x 2n tiles of 32x32; snake over quadrants:
// P1: {m0,m1}xn0  P2: {m0,m1}xn1  P3: {m2,m3}xn1  P4: {m2,m3}xn0.
// Stage kt+2 into freed regions: P2: A slabs{0,2}; P3: B all; P4: A{1,3}.
// Tile-end VMCNT(8): kt+1's 8 loads landed, kt+2's 8 stay in flight.
// ---------------------------------------------------------------------------
#define BM 256
#define BN 256
#define BK 64
#define KTILES (DDIM / BK)

__global__ __launch_bounds__(512, 2) void gemm_rowsum(
    const ushort* __restrict__ z1, const ushort* __restrict__ z2,
    float* __restrict__ partial)
{
  __shared__ __align__(16) ushort As[2][BM * BK];   // 2 x 32 KiB
  __shared__ __align__(16) ushort Bs[2][BN * BK];   // 2 x 32 KiB

  const int bid = blockIdx.x;
  const int bi = bid >> 5;          // 32 row-blocks
  const int bj = bid & 31;          // 32 col-blocks
  const int brow = bi * BM;
  const int bcol = bj * BN;
  const int t = threadIdx.x;
  const int w = t >> 6;             // wave 0..7
  const int lane = t & 63;
  const int wr = w >> 2;            // 0..1: A rows wr*128
  const int wc = w & 3;             // 0..3: B cols wc*64
  const int l31 = lane & 31;
  const int l7  = lane & 7;
  const int lhi = lane >> 5;        // 0..1
  const int sr = lane >> 3;         // stage: row within 8-row slab
  const int sc = lane & 7;          // stage: 16B chunk
  const int ssw = ((sc ^ sr) << 3); // pre-swizzled global elem offset

  f32x16 acc[4][2];
  #pragma unroll
  for (int i = 0; i < 4; ++i)
    #pragma unroll
    for (int j = 0; j < 2; ++j)
      acc[i][j] = (f32x16)(0.f);

  // ---- staging (linear LDS dest, swizzled global src); slab = 64 rows ----
#define STAGE_A(S, BUF, K0)                                                   \
  gload_lds16(z1 + (size_t)(brow + (S)*64 + w*8 + sr) * DDIM + (K0) + ssw,    \
              &As[BUF][((S)*64 + w*8) * BK])
#define STAGE_B(S, BUF, K0)                                                   \
  gload_lds16(z2 + (size_t)(bcol + (S)*64 + w*8 + sr) * DDIM + (K0) + ssw,    \
              &Bs[BUF][((S)*64 + w*8) * BK])

  // ---- swizzled ds_read of one 32x32x16 fragment chunk ----
  // A: row = wr*128 + mtile*32 + l31, k-chunk(8 elems) = ks*2 + lhi, XOR l7
#define SWZ32(KS) ((((KS)*2 + lhi) ^ l7) << 3)
#define READ_A32(DST, HALF, BUF)                                              \
  _Pragma("unroll")                                                           \
  for (int mi = 0; mi < 2; ++mi)                                              \
    _Pragma("unroll")                                                         \
    for (int ks = 0; ks < 4; ++ks)                                            \
      DST[mi*4+ks] = *(const short8*)                                         \
        &As[BUF][(wr*128 + ((HALF)*2+mi)*32 + l31)*BK + SWZ32(ks)];
#define READ_B32(DST, NT, BUF)                                                \
  _Pragma("unroll")                                                           \
  for (int ks = 0; ks < 4; ++ks)                                              \
    DST[ks] = *(const short8*)                                                \
      &Bs[BUF][(wc*64 + (NT)*32 + l31)*BK + SWZ32(ks)];

  // 8 MFMA-32 per phase: 2 m-tiles x K=64; ks outer, mi inner (dep dist 2)
#define QUAD32(MT, NT, AA, BB)                                                \
  _Pragma("unroll")                                                           \
  for (int ks = 0; ks < 4; ++ks)                                              \
    _Pragma("unroll")                                                         \
    for (int mi = 0; mi < 2; ++mi)                                            \
      acc[(MT)+mi][NT] = __builtin_amdgcn_mfma_f32_32x32x16_bf16(             \
          AA[mi*4+ks], BB[ks], acc[(MT)+mi][NT], 0, 0, 0);

  // prologue: stage tile 0 -> buf0, tile 1 -> buf1; counted wait for tile 0
  #pragma unroll
  for (int s = 0; s < 4; ++s) { STAGE_A(s, 0, 0); STAGE_B(s, 0, 0); }
  #pragma unroll
  for (int s = 0; s < 4; ++s) { STAGE_A(s, 1, BK); STAGE_B(s, 1, BK); }
  VMCNT(8);          // tile 0's 8 loads landed; tile 1's stay in flight
  SBAR();

  short8 a[8], b0[4], b1[4];

  #pragma unroll 2
  for (int kt = 0; kt < KTILES; ++kt) {
    const int cur = kt & 1;
    const int k2 = (kt + 2) * BK;
    const bool pf2 = (kt + 2 < KTILES);

    // ---- P1: read A m{0,1} (8) + B n0 (4) ----
    READ_A32(a, 0, cur);
    READ_B32(b0, 0, cur);
    SBAR();
    PRIO(1); QUAD32(0, 0, a, b0); PRIO(0);
    SBAR();

    // ---- P2: read B n1 (4); stage next-next A slabs {0,2} (read in P1) ----
    READ_B32(b1, 1, cur);
    if (pf2) { STAGE_A(0, cur, k2); STAGE_A(2, cur, k2); }
    SBAR();
    PRIO(1); QUAD32(0, 1, a, b1); PRIO(0);
    SBAR();

    // ---- P3: read A m{2,3} (8, last As reads); stage next-next B (all) ----
    READ_A32(a, 1, cur);
    if (pf2) { STAGE_B(0, cur, k2); STAGE_B(1, cur, k2);
               STAGE_B(2, cur, k2); STAGE_B(3, cur, k2); }
    SBAR();
    PRIO(1); QUAD32(2, 1, a, b1); PRIO(0);
    SBAR();

    // ---- P4: stage next-next A slabs {1,3}; MFMA; counted tile wait ----
    if (pf2) { STAGE_A(1, cur, k2); STAGE_A(3, cur, k2); }
    PRIO(1); QUAD32(2, 0, a, b0); PRIO(0);
    if (pf2)                   VMCNT(8);   // kt+1 ready; kt+2 in flight
    else if (kt + 1 < KTILES)  VMCNT(0);   // kt==14: drain last tile
    SBAR();
  }

  // ---- epilogue: exp + per-row sum over this block's 256 cols ----
  // 32x32 C/D layout (m74/m101): col = l31, row = (r&3) + 8*(r>>2) + 4*lhi
  float* rs = (float*)&As[0][0];   // [4][256] f32, aliased (all loads drained)
  #pragma unroll
  for (int mt = 0; mt < 4; ++mt) {
    #pragma unroll
    for (int r = 0; r < 16; ++r) {
      float s = __expf(acc[mt][0][r]) + __expf(acc[mt][1][r]);
      s += __shfl_xor(s, 1);
      s += __shfl_xor(s, 2);
      s += __shfl_xor(s, 4);
      s += __shfl_xor(s, 8);
      s += __shfl_xor(s, 16);
      if (l31 == 0) {
        const int row_local = wr*128 + mt*32 + (r & 3) + 8*(r >> 2) + 4*lhi;
        rs[wc * 256 + row_local] = s;
      }
    }
  }
  __syncthreads();
  if (t < 256)
    partial[(size_t)bj * NROW + brow + t] =
        rs[t] + rs[256 + t] + rs[512 + t] + rs[768 + t];
}

// ---------------------------------------------------------------------------
// Kernel 3: per-row loss = log(sum of 32 partials) - diag; block partial sums.
// ---------------------------------------------------------------------------
__global__ __launch_bounds__(256) void rowloss(
    const float* __restrict__ partial, const float* __restrict__ diag,
    float* __restrict__ blocksum)
{
  const int i = blockIdx.x * 256 + threadIdx.x;
  float s = 0.f;
  #pragma unroll 8
  for (int b = 0; b < 32; ++b) s += partial[(size_t)b * NROW + i];
  float loss = logf(s) - diag[i];
  #pragma unroll
  for (int m = 1; m < 64; m <<= 1) loss += __shfl_xor(loss, m);
  __shared__ float red[4];
  if ((threadIdx.x & 63) == 0) red[threadIdx.x >> 6] = loss;
  __syncthreads();
  if (threadIdx.x == 0)
    blocksum[blockIdx.x] = red[0] + red[1] + red[2] + red[3];
}

__global__ void finalize(const float* __restrict__ blocksum,
                         float* __restrict__ out)
{
  float s = (threadIdx.x < 32) ? blocksum[threadIdx.x] : 0.f;
  #pragma unroll
  for (int m = 1; m < 64; m <<= 1) s += __shfl_xor(s, m);
  if (threadIdx.x == 0) out[0] = s * (1.0f / NROW);
}

// ---------------------------------------------------------------------------
extern "C" void kernel_launch(void* const* d_in, const int* in_sizes, int n_in,
                              void* d_out, int out_size, void* d_ws, size_t ws_size,
                              hipStream_t stream) {
  const float* v1 = (const float*)d_in[0];
  const float* v2 = (const float*)d_in[1];
  float* out = (float*)d_out;

  char* ws = (char*)d_ws;
  // layout: z1 (16MB) | z2 (16MB) | diag (32KB) | partial (1MB) | blocksum
  ushort* z1 = (ushort*)ws;
  ushort* z2 = (ushort*)(ws + (size_t)NROW * DDIM * 2);
  float* diag = (float*)(ws + (size_t)NROW * DDIM * 4);
  float* partial = (float*)(ws + (size_t)NROW * DDIM * 4 + (size_t)NROW * 4);
  float* blocksum = (float*)(ws + (size_t)NROW * DDIM * 4 + (size_t)NROW * 4
                             + (size_t)32 * NROW * 4);

  normalize_diag<<<NROW, 256, 0, stream>>>(v1, v2, z1, z2, diag);
  gemm_rowsum<<<(NROW / BM) * (NROW / BN), 512, 0, stream>>>(z1, z2, partial);
  rowloss<<<NROW / 256, 256, 0, stream>>>(partial, diag, blocksum);
  finalize<<<1, 64, 0, stream>>>(blocksum, out);
}

// Round 6
// 157.514 us; speedup vs baseline: 1.2306x; 1.2306x over previous
//
#include <hip/hip_runtime.h>
#include <hip/hip_bf16.h>

#define NROW 8192
#define DDIM 1024
#define TINV 2.0f   // 1 / TEMPERATURE

typedef __attribute__((ext_vector_type(4))) float f32x4;

__device__ __forceinline__ void gload_lds16(const void* g, void* l) {
  __builtin_amdgcn_global_load_lds(
      (const __attribute__((address_space(1))) void*)g,
      (__attribute__((address_space(3))) void*)l, 16, 0, 0);
}

#define SBAR()  __builtin_amdgcn_s_barrier()
#define PRIO(x) __builtin_amdgcn_s_setprio(x)
#define VMCNT(N) asm volatile("s_waitcnt vmcnt(" #N ")" ::: "memory")

// ---- manual f32 -> fp8 e4m3fn (OCP), RNE, saturating; no API risk ----
__device__ __forceinline__ unsigned f2fp8(float x) {
  unsigned b = __float_as_uint(x);
  unsigned sgn = (b >> 24) & 0x80u;
  float af = __uint_as_float(b & 0x7FFFFFFFu);
  if (af >= 448.0f) return sgn | 0x7Eu;          // clamp to max finite
  if (af < 0.015625f) {                          // subnormal: units of 2^-9
    unsigned q = (unsigned)__float2int_rn(af * 512.0f);
    return sgn | q;                              // q==8 naturally -> 2^-6
  }
  unsigned ab = b & 0x7FFFFFFFu;
  unsigned m  = ab & 0x7FFFFFu;
  unsigned m3 = m >> 20;
  unsigned rem = m & 0xFFFFFu;
  unsigned rnd = (rem > 0x80000u) || (rem == 0x80000u && (m3 & 1u));
  unsigned e  = (ab >> 23) - 120u;               // fp8 biased exponent
  return sgn | ((e << 3) + m3 + rnd);            // mantissa carry -> exp
}

// ---------------------------------------------------------------------------
// Kernel 1: per-row L2 norms, diag (fp32-exact), fp8 normalized copies
// (z1 pre-scaled by 1/T; power-of-2 scale = exact).
// ---------------------------------------------------------------------------
__global__ __launch_bounds__(256) void normalize_diag(
    const float* __restrict__ v1, const float* __restrict__ v2,
    unsigned* __restrict__ z1, unsigned* __restrict__ z2,
    float* __restrict__ diag)
{
  const int row = blockIdx.x;
  const int t = threadIdx.x;
  const float4 a = ((const float4*)(v1 + (size_t)row * DDIM))[t];
  const float4 b = ((const float4*)(v2 + (size_t)row * DDIM))[t];
  float s1 = a.x*a.x + a.y*a.y + a.z*a.z + a.w*a.w;
  float s2 = b.x*b.x + b.y*b.y + b.z*b.z + b.w*b.w;
  float sd = a.x*b.x + a.y*b.y + a.z*b.z + a.w*b.w;
  #pragma unroll
  for (int m = 1; m < 64; m <<= 1) {
    s1 += __shfl_xor(s1, m);
    s2 += __shfl_xor(s2, m);
    sd += __shfl_xor(sd, m);
  }
  __shared__ float red[3][4];
  const int w = t >> 6;
  if ((t & 63) == 0) { red[0][w] = s1; red[1][w] = s2; red[2][w] = sd; }
  __syncthreads();
  s1 = red[0][0] + red[0][1] + red[0][2] + red[0][3];
  s2 = red[1][0] + red[1][1] + red[1][2] + red[1][3];
  sd = red[2][0] + red[2][1] + red[2][2] + red[2][3];
  const float i1 = 1.0f / fmaxf(sqrtf(s1), 1e-12f);
  const float i2 = 1.0f / fmaxf(sqrtf(s2), 1e-12f);
  if (t == 0) diag[row] = sd * i1 * i2 * TINV;
  const float sc1 = i1 * TINV;
  unsigned o1 = f2fp8(a.x*sc1) | (f2fp8(a.y*sc1) << 8)
              | (f2fp8(a.z*sc1) << 16) | (f2fp8(a.w*sc1) << 24);
  unsigned o2 = f2fp8(b.x*i2)  | (f2fp8(b.y*i2)  << 8)
              | (f2fp8(b.z*i2) << 16) | (f2fp8(b.w*i2)  << 24);
  z1[(size_t)row * 256 + t] = o1;
  z2[(size_t)row * 256 + t] = o2;
}

// ---------------------------------------------------------------------------
// Kernel 2: 256x256-tile fp8 GEMM (sim = z1*z2^T) + fused exp-rowsum.
// 8 waves (2M x 4N), BK=64 (bytes), 2-buffer LDS (64 KiB total), counted
// VMCNT(4), T5 setprio, R4 phase skeleton, 16x16x32 fp8 MFMA.
// LDS slab layout (per 16 rows): [4 chunk-planes][16 rows][16B] -- row
// stride 16B makes ds_read_b64 fragments 2-way/bank (free), no swizzle.
// Stage: lane l -> (row=l&15, chunk=l>>4); LDS dest linear (base+l*16).
// ---------------------------------------------------------------------------
#define BM 256
#define BN 256
#define BK 64
#define KTILES (DDIM / BK)

__global__ __launch_bounds__(512, 2) void gemm_rowsum(
    const unsigned char* __restrict__ z1b,
    const unsigned char* __restrict__ z2b,
    float* __restrict__ partial)
{
  __shared__ __align__(16) unsigned char As[2][BM * BK];   // 2 x 16 KiB
  __shared__ __align__(16) unsigned char Bs[2][BN * BK];   // 2 x 16 KiB

  const int bid = blockIdx.x;
  const int bi = bid >> 5;          // 32 row-blocks
  const int bj = bid & 31;          // 32 col-blocks
  const int brow = bi * BM;
  const int bcol = bj * BN;
  const int t = threadIdx.x;
  const int w = t >> 6;             // wave 0..7
  const int lane = t & 63;
  const int wr = w >> 2;            // 0..1: A rows wr*128
  const int wc = w & 3;             // 0..3: B cols wc*64
  const int lcol = lane & 15;
  const int lgrp = lane >> 4;       // 0..3
  const int jhi = lgrp >> 1;        // plane bit from k-group
  const int jlo = (lgrp & 1) * 8;   // 8B half within 16B chunk
  const int lane_off = lcol * 16 + jlo;
  const int r16 = lane & 15;        // stage: row within slab
  const int c16 = lane >> 4;        // stage: 16B chunk (plane)

  f32x4 acc[8][4];
  #pragma unroll
  for (int i = 0; i < 8; ++i)
    #pragma unroll
    for (int j = 0; j < 4; ++j)
      acc[i][j] = (f32x4){0.f, 0.f, 0.f, 0.f};

  // ---- staging: one slab (16 rows x 64B) per instruction; 2 A + 2 B /wave
#define STAGE_A8(I, BUF, K0)                                                  \
  gload_lds16(z1b + (size_t)(brow + (2*w + (I))*16 + r16) * DDIM + (K0)       \
                  + c16*16,                                                   \
              &As[BUF][(2*w + (I)) * 1024])
#define STAGE_B8(I, BUF, K0)                                                  \
  gload_lds16(z2b + (size_t)(bcol + (2*w + (I))*16 + r16) * DDIM + (K0)       \
                  + c16*16,                                                   \
              &Bs[BUF][(2*w + (I)) * 1024])

  // ---- fragment read: slab plane layout, 8B per lane (ds_read_b64) ----
#define RD8(ARR, SLAB, KK)                                                    \
  (*(const long*)&ARR[(SLAB)*1024 + ((KK)*2 + jhi)*256 + lane_off])
#define READ_A8(DST, HALF, BUF)                                               \
  _Pragma("unroll")                                                           \
  for (int m = 0; m < 4; ++m) {                                               \
    const int slab_ = wr*8 + (HALF)*4 + m;                                    \
    DST[m*2+0] = RD8(As[BUF], slab_, 0);                                      \
    DST[m*2+1] = RD8(As[BUF], slab_, 1);                                      \
  }
#define READ_B8(DST, HALF, BUF)                                               \
  _Pragma("unroll")                                                           \
  for (int n = 0; n < 2; ++n) {                                               \
    const int slab_ = wc*4 + (HALF)*2 + n;                                    \
    DST[n*2+0] = RD8(Bs[BUF], slab_, 0);                                      \
    DST[n*2+1] = RD8(Bs[BUF], slab_, 1);                                      \
  }

#define QUAD8(MB, NB, AA, BB)                                                 \
  _Pragma("unroll")                                                           \
  for (int kk = 0; kk < 2; ++kk)                                              \
    _Pragma("unroll")                                                         \
    for (int m = 0; m < 4; ++m)                                               \
      _Pragma("unroll")                                                       \
      for (int n = 0; n < 2; ++n)                                             \
        acc[(MB)+m][(NB)+n] = __builtin_amdgcn_mfma_f32_16x16x32_fp8_fp8(     \
            AA[m*2+kk], BB[n*2+kk], acc[(MB)+m][(NB)+n], 0, 0, 0);

  // prologue: stage tile 0 -> buf0, tile 1 -> buf1; counted wait for tile 0
  STAGE_A8(0, 0, 0); STAGE_A8(1, 0, 0); STAGE_B8(0, 0, 0); STAGE_B8(1, 0, 0);
  STAGE_A8(0, 1, BK); STAGE_A8(1, 1, BK);
  STAGE_B8(0, 1, BK); STAGE_B8(1, 1, BK);
  VMCNT(4);          // tile 0's 4 loads landed; tile 1's stay in flight
  SBAR();

  long a[8], b0[4], b1[4];

  #pragma unroll 2
  for (int kt = 0; kt < KTILES; ++kt) {
    const int cur = kt & 1;
    const int k2 = (kt + 2) * BK;
    const bool pf2 = (kt + 2 < KTILES);

    // ---- P1: read A-h0 (8 b64) + B-h0 (4 b64) ----
    READ_A8(a, 0, cur);
    READ_B8(b0, 0, cur);
    SBAR();
    PRIO(1); QUAD8(0, 0, a, b0); PRIO(0);
    SBAR();

    // ---- P2: read B-h1 (4; last Bs[cur] reads) ----
    READ_B8(b1, 1, cur);
    SBAR();
    PRIO(1); QUAD8(0, 2, a, b1); PRIO(0);
    SBAR();

    // ---- P3: read A-h1 (8; last As[cur] reads); stage next-next B ----
    READ_A8(a, 1, cur);
    if (pf2) { STAGE_B8(0, cur, k2); STAGE_B8(1, cur, k2); }
    SBAR();
    PRIO(1); QUAD8(4, 2, a, b1); PRIO(0);
    SBAR();

    // ---- P4: stage next-next A; MFMA; counted tile-boundary wait ----
    if (pf2) { STAGE_A8(0, cur, k2); STAGE_A8(1, cur, k2); }
    PRIO(1); QUAD8(4, 0, a, b0); PRIO(0);
    if (pf2)                   VMCNT(4);   // kt+1 ready; kt+2 in flight
    else if (kt + 1 < KTILES)  VMCNT(0);   // kt==14: drain last tile
    SBAR();
  }

  // ---- epilogue: exp + per-row sum over this block's 256 cols ----
  // 16x16 C/D layout (dtype-independent): col = lane&15, row = lgrp*4 + reg.
  float* rs = (float*)&As[0][0];   // [4][256] f32, aliased (all loads drained)
  #pragma unroll
  for (int m = 0; m < 8; ++m) {
    #pragma unroll
    for (int r = 0; r < 4; ++r) {
      float s = __expf(acc[m][0][r]) + __expf(acc[m][1][r])
              + __expf(acc[m][2][r]) + __expf(acc[m][3][r]);
      s += __shfl_xor(s, 1);
      s += __shfl_xor(s, 2);
      s += __shfl_xor(s, 4);
      s += __shfl_xor(s, 8);
      if (lcol == 0) rs[wc * 256 + wr * 128 + m * 16 + lgrp * 4 + r] = s;
    }
  }
  __syncthreads();
  if (t < 256)
    partial[(size_t)bj * NROW + brow + t] =
        rs[t] + rs[256 + t] + rs[512 + t] + rs[768 + t];
}

// ---------------------------------------------------------------------------
// Kernel 3: per-row loss = log(sum of 32 partials) - diag; block partial sums.
// ---------------------------------------------------------------------------
__global__ __launch_bounds__(256) void rowloss(
    const float* __restrict__ partial, const float* __restrict__ diag,
    float* __restrict__ blocksum)
{
  const int i = blockIdx.x * 256 + threadIdx.x;
  float s = 0.f;
  #pragma unroll 8
  for (int b = 0; b < 32; ++b) s += partial[(size_t)b * NROW + i];
  float loss = logf(s) - diag[i];
  #pragma unroll
  for (int m = 1; m < 64; m <<= 1) loss += __shfl_xor(loss, m);
  __shared__ float red[4];
  if ((threadIdx.x & 63) == 0) red[threadIdx.x >> 6] = loss;
  __syncthreads();
  if (threadIdx.x == 0)
    blocksum[blockIdx.x] = red[0] + red[1] + red[2] + red[3];
}

__global__ void finalize(const float* __restrict__ blocksum,
                         float* __restrict__ out)
{
  float s = (threadIdx.x < 32) ? blocksum[threadIdx.x] : 0.f;
  #pragma unroll
  for (int m = 1; m < 64; m <<= 1) s += __shfl_xor(s, m);
  if (threadIdx.x == 0) out[0] = s * (1.0f / NROW);
}

// ---------------------------------------------------------------------------
extern "C" void kernel_launch(void* const* d_in, const int* in_sizes, int n_in,
                              void* d_out, int out_size, void* d_ws, size_t ws_size,
                              hipStream_t stream) {
  const float* v1 = (const float*)d_in[0];
  const float* v2 = (const float*)d_in[1];
  float* out = (float*)d_out;

  char* ws = (char*)d_ws;
  // layout: z1 (8MB fp8) | z2 (8MB fp8) | diag (32KB) | partial (1MB) | bsum
  unsigned char* z1 = (unsigned char*)ws;
  unsigned char* z2 = (unsigned char*)(ws + (size_t)NROW * DDIM);
  float* diag = (float*)(ws + (size_t)NROW * DDIM * 2);
  float* partial = (float*)(ws + (size_t)NROW * DDIM * 2 + (size_t)NROW * 4);
  float* blocksum = (float*)(ws + (size_t)NROW * DDIM * 2 + (size_t)NROW * 4
                             + (size_t)32 * NROW * 4);

  normalize_diag<<<NROW, 256, 0, stream>>>(v1, v2, (unsigned*)z1, (unsigned*)z2,
                                           diag);
  gemm_rowsum<<<(NROW / BM) * (NROW / BN), 512, 0, stream>>>(z1, z2, partial);
  rowloss<<<NROW / 256, 256, 0, stream>>>(partial, diag, blocksum);
  finalize<<<1, 64, 0, stream>>>(blocksum, out);
}

// Round 7
// 116.736 us; speedup vs baseline: 1.6604x; 1.3493x over previous
//
#include <hip/hip_runtime.h>
#include <hip/hip_bf16.h>

#define NROW 8192
#define DDIM 1024          // bytes per fp8 row
#define TINV 2.0f          // 1 / TEMPERATURE
#define SCALE1 0x7F7F7F7F  // e8m0 = 127 in every byte -> scale 1.0

typedef __attribute__((ext_vector_type(4))) float f32x4;
typedef __attribute__((ext_vector_type(4))) int   i32x4;
typedef __attribute__((ext_vector_type(8))) int   i32x8;

__device__ __forceinline__ void gload_lds16(const void* g, void* l) {
  __builtin_amdgcn_global_load_lds(
      (const __attribute__((address_space(1))) void*)g,
      (__attribute__((address_space(3))) void*)l, 16, 0, 0);
}

#define SBAR()  __builtin_amdgcn_s_barrier()
#define PRIO(x) __builtin_amdgcn_s_setprio(x)
#define VMCNT(N) asm volatile("s_waitcnt vmcnt(" #N ")" ::: "memory")

// ---- manual f32 -> fp8 e4m3fn (OCP), RNE, saturating ----
__device__ __forceinline__ unsigned f2fp8(float x) {
  unsigned b = __float_as_uint(x);
  unsigned sgn = (b >> 24) & 0x80u;
  float af = __uint_as_float(b & 0x7FFFFFFFu);
  if (af >= 448.0f) return sgn | 0x7Eu;
  if (af < 0.015625f) {
    unsigned q = (unsigned)__float2int_rn(af * 512.0f);
    return sgn | q;
  }
  unsigned ab = b & 0x7FFFFFFFu;
  unsigned m  = ab & 0x7FFFFFu;
  unsigned m3 = m >> 20;
  unsigned rem = m & 0xFFFFFu;
  unsigned rnd = (rem > 0x80000u) || (rem == 0x80000u && (m3 & 1u));
  unsigned e  = (ab >> 23) - 120u;
  return sgn | ((e << 3) + m3 + rnd);
}

// ---------------------------------------------------------------------------
// Kernel 1: per-row L2 norms, diag (fp32-exact), fp8 normalized copies
// (z1 pre-scaled by 1/T; power-of-2 scale = exact).
// ---------------------------------------------------------------------------
__global__ __launch_bounds__(256) void normalize_diag(
    const float* __restrict__ v1, const float* __restrict__ v2,
    unsigned* __restrict__ z1, unsigned* __restrict__ z2,
    float* __restrict__ diag)
{
  const int row = blockIdx.x;
  const int t = threadIdx.x;
  const float4 a = ((const float4*)(v1 + (size_t)row * 1024))[t];
  const float4 b = ((const float4*)(v2 + (size_t)row * 1024))[t];
  float s1 = a.x*a.x + a.y*a.y + a.z*a.z + a.w*a.w;
  float s2 = b.x*b.x + b.y*b.y + b.z*b.z + b.w*b.w;
  float sd = a.x*b.x + a.y*b.y + a.z*b.z + a.w*b.w;
  #pragma unroll
  for (int m = 1; m < 64; m <<= 1) {
    s1 += __shfl_xor(s1, m);
    s2 += __shfl_xor(s2, m);
    sd += __shfl_xor(sd, m);
  }
  __shared__ float red[3][4];
  const int w = t >> 6;
  if ((t & 63) == 0) { red[0][w] = s1; red[1][w] = s2; red[2][w] = sd; }
  __syncthreads();
  s1 = red[0][0] + red[0][1] + red[0][2] + red[0][3];
  s2 = red[1][0] + red[1][1] + red[1][2] + red[1][3];
  sd = red[2][0] + red[2][1] + red[2][2] + red[2][3];
  const float i1 = 1.0f / fmaxf(sqrtf(s1), 1e-12f);
  const float i2 = 1.0f / fmaxf(sqrtf(s2), 1e-12f);
  if (t == 0) diag[row] = sd * i1 * i2 * TINV;
  const float sc1 = i1 * TINV;
  unsigned o1 = f2fp8(a.x*sc1) | (f2fp8(a.y*sc1) << 8)
              | (f2fp8(a.z*sc1) << 16) | (f2fp8(a.w*sc1) << 24);
  unsigned o2 = f2fp8(b.x*i2)  | (f2fp8(b.y*i2)  << 8)
              | (f2fp8(b.z*i2) << 16) | (f2fp8(b.w*i2)  << 24);
  z1[(size_t)row * 256 + t] = o1;
  z2[(size_t)row * 256 + t] = o2;
}

// ---------------------------------------------------------------------------
// Kernel 2: 128x128-tile MX-fp8 GEMM (sim = z1*z2^T) + fused exp-rowsum.
// mfma_scale_f32_16x16x128_f8f6f4 with UNIT scales (0x7F = 2^0): numerics
// identical to plain fp8; 2.27x MFMA rate (m148: 1628 TF on this structure).
// 4 waves (2M x 2N), BK=128 bytes, 2-buffer LDS (64 KiB), counted VMCNT(8)
// two-tiles-deep, T5 setprio. LDS reads use R4's verified 0-conflict b128
// geometry: row stride 128B, chunk = (o*4+lgrp) ^ (lcol&7), staged with
// pre-swizzled global source (both-sides rule). A/B use the SAME read
// geometry so the byte->k permutation P cancels in the dot product.
// ---------------------------------------------------------------------------
#define BM 128
#define BN 128
#define BK 128
#define KTILES (DDIM / BK)

__global__ __launch_bounds__(256, 2) void gemm_rowsum(
    const unsigned char* __restrict__ z1b,
    const unsigned char* __restrict__ z2b,
    float* __restrict__ partial)
{
  __shared__ __align__(16) unsigned char As[2][BM * BK];   // 2 x 16 KiB
  __shared__ __align__(16) unsigned char Bs[2][BN * BK];   // 2 x 16 KiB

  const int bid = blockIdx.x;
  const int bi = bid >> 6;          // 64 row-blocks
  const int bj = bid & 63;          // 64 col-blocks
  const int brow = bi * BM;
  const int bcol = bj * BN;
  const int t = threadIdx.x;
  const int w = t >> 6;             // wave 0..3
  const int lane = t & 63;
  const int wr = w >> 1;            // 0..1: A rows wr*64
  const int wc = w & 1;             // 0..1: B cols wc*64
  const int lcol = lane & 15;
  const int lgrp = lane >> 4;       // 0..3
  const int l7 = lcol & 7;
  const int sr = lane >> 3;         // stage: row within 8-row slab (0..7)
  const int sc = lane & 7;          // stage: 16B chunk (0..7)
  const int ssw = (sc ^ sr) << 4;   // pre-swizzled global byte offset

  f32x4 acc[4][4];
  #pragma unroll
  for (int i = 0; i < 4; ++i)
    #pragma unroll
    for (int j = 0; j < 4; ++j)
      acc[i][j] = (f32x4){0.f, 0.f, 0.f, 0.f};

  // ---- staging: slab = 8 rows x 128B = 1KB per gload; 4 A + 4 B per wave
#define STAGE_A(S, BUF, K0)                                                   \
  gload_lds16(z1b + (size_t)(brow + w*32 + (S)*8 + sr) * DDIM + (K0) + ssw,   \
              &As[BUF][(w*4 + (S)) * 1024])
#define STAGE_B(S, BUF, K0)                                                   \
  gload_lds16(z2b + (size_t)(bcol + w*32 + (S)*8 + sr) * DDIM + (K0) + ssw,   \
              &Bs[BUF][(w*4 + (S)) * 1024])

  // ---- fragment read: two b128 per operand, R4 0-conflict geometry ----
  // LDS[row][c] holds global k-chunk (c ^ (row&7)); read chunk
  // (o*4+lgrp)^(row&7) -> delivers k-chunk o*4+lgrp, row-independent.
#define RDFRAG(DST, ARR, ROWB)                                                \
  do {                                                                        \
    const int rb_ = (ROWB);                                                   \
    i32x4 lo_ = *(const i32x4*)&ARR[rb_*128 + ((lgrp)     ^ l7)*16];          \
    i32x4 hi_ = *(const i32x4*)&ARR[rb_*128 + ((4 + lgrp) ^ l7)*16];          \
    DST[0]=lo_[0]; DST[1]=lo_[1]; DST[2]=lo_[2]; DST[3]=lo_[3];               \
    DST[4]=hi_[0]; DST[5]=hi_[1]; DST[6]=hi_[2]; DST[7]=hi_[3];               \
  } while (0)

#define RA(MT, BUF, DST) RDFRAG(DST, As[BUF], wr*64 + (MT)*16 + lcol)
#define RB(NT, BUF, DST) RDFRAG(DST, Bs[BUF], wc*64 + (NT)*16 + lcol)

#define MF(MT, NT, AA, BB)                                                    \
  acc[MT][NT] = __builtin_amdgcn_mfma_scale_f32_16x16x128_f8f6f4(             \
      AA, BB, acc[MT][NT], 0, 0, 0, SCALE1, 0, SCALE1)

  // prologue: stage tile 0 -> buf0, tile 1 -> buf1; counted wait for tile 0
  #pragma unroll
  for (int s = 0; s < 4; ++s) { STAGE_A(s, 0, 0); STAGE_B(s, 0, 0); }
  #pragma unroll
  for (int s = 0; s < 4; ++s) { STAGE_A(s, 1, BK); STAGE_B(s, 1, BK); }
  VMCNT(8);          // tile 0's 8 loads landed; tile 1's stay in flight
  SBAR();

  i32x8 am0, am1, bn0, bn1, bn2, bn3;

  #pragma unroll 2
  for (int kt = 0; kt < KTILES; ++kt) {
    const int cur = kt & 1;
    const int k2 = (kt + 2) * BK;
    const bool pf2 = (kt + 2 < KTILES);

    // ---- P1: read A m0,m1 + B n0,n1 (8 b128) ----
    RA(0, cur, am0); RA(1, cur, am1);
    RB(0, cur, bn0); RB(1, cur, bn1);
    SBAR();
    PRIO(1); MF(0,0,am0,bn0); MF(1,1,am1,bn1);
             MF(0,1,am0,bn1); MF(1,0,am1,bn0); PRIO(0);
    SBAR();

    // ---- P2: read B n2,n3 (last Bs[cur] reads) ----
    RB(2, cur, bn2); RB(3, cur, bn3);
    SBAR();
    PRIO(1); MF(0,2,am0,bn2); MF(1,3,am1,bn3);
             MF(0,3,am0,bn3); MF(1,2,am1,bn2); PRIO(0);
    SBAR();

    // ---- P3: read A m2,m3 (last As[cur] reads); stage next-next B ----
    RA(2, cur, am0); RA(3, cur, am1);
    if (pf2) { STAGE_B(0, cur, k2); STAGE_B(1, cur, k2);
               STAGE_B(2, cur, k2); STAGE_B(3, cur, k2); }
    SBAR();
    PRIO(1); MF(2,2,am0,bn2); MF(3,3,am1,bn3);
             MF(2,3,am0,bn3); MF(3,2,am1,bn2); PRIO(0);
    SBAR();

    // ---- P4: stage next-next A; MFMA; counted tile-boundary wait ----
    if (pf2) { STAGE_A(0, cur, k2); STAGE_A(1, cur, k2);
               STAGE_A(2, cur, k2); STAGE_A(3, cur, k2); }
    PRIO(1); MF(2,0,am0,bn0); MF(3,1,am1,bn1);
             MF(2,1,am0,bn1); MF(3,0,am1,bn0); PRIO(0);
    if (pf2)                   VMCNT(8);   // kt+1 ready; kt+2 in flight
    else if (kt + 1 < KTILES)  VMCNT(0);   // kt==6: drain last tile
    SBAR();
  }

  // ---- epilogue: exp + per-row sum over this block's 128 cols ----
  // C/D layout (shape-determined): col = lane&15, row = lgrp*4 + reg.
  float* rs = (float*)&As[0][0];   // [2][128] f32, aliased (loads drained)
  #pragma unroll
  for (int mt = 0; mt < 4; ++mt) {
    #pragma unroll
    for (int r = 0; r < 4; ++r) {
      float s = __expf(acc[mt][0][r]) + __expf(acc[mt][1][r])
              + __expf(acc[mt][2][r]) + __expf(acc[mt][3][r]);
      s += __shfl_xor(s, 1);
      s += __shfl_xor(s, 2);
      s += __shfl_xor(s, 4);
      s += __shfl_xor(s, 8);
      if (lcol == 0) rs[wc * 128 + wr * 64 + mt * 16 + lgrp * 4 + r] = s;
    }
  }
  __syncthreads();
  if (t < 128)
    partial[(size_t)bj * NROW + brow + t] = rs[t] + rs[128 + t];
}

// ---------------------------------------------------------------------------
// Kernel 3: per-row loss = log(sum of 64 partials) - diag; block partial sums.
// ---------------------------------------------------------------------------
__global__ __launch_bounds__(256) void rowloss(
    const float* __restrict__ partial, const float* __restrict__ diag,
    float* __restrict__ blocksum)
{
  const int i = blockIdx.x * 256 + threadIdx.x;
  float s = 0.f;
  #pragma unroll 8
  for (int b = 0; b < 64; ++b) s += partial[(size_t)b * NROW + i];
  float loss = logf(s) - diag[i];
  #pragma unroll
  for (int m = 1; m < 64; m <<= 1) loss += __shfl_xor(loss, m);
  __shared__ float red[4];
  if ((threadIdx.x & 63) == 0) red[threadIdx.x >> 6] = loss;
  __syncthreads();
  if (threadIdx.x == 0)
    blocksum[blockIdx.x] = red[0] + red[1] + red[2] + red[3];
}

__global__ void finalize(const float* __restrict__ blocksum,
                         float* __restrict__ out)
{
  float s = (threadIdx.x < 32) ? blocksum[threadIdx.x] : 0.f;
  #pragma unroll
  for (int m = 1; m < 64; m <<= 1) s += __shfl_xor(s, m);
  if (threadIdx.x == 0) out[0] = s * (1.0f / NROW);
}

// ---------------------------------------------------------------------------
extern "C" void kernel_launch(void* const* d_in, const int* in_sizes, int n_in,
                              void* d_out, int out_size, void* d_ws, size_t ws_size,
                              hipStream_t stream) {
  const float* v1 = (const float*)d_in[0];
  const float* v2 = (const float*)d_in[1];
  float* out = (float*)d_out;

  char* ws = (char*)d_ws;
  // layout: z1 (8MB fp8) | z2 (8MB fp8) | diag (32KB) | partial (2MB) | bsum
  unsigned char* z1 = (unsigned char*)ws;
  unsigned char* z2 = (unsigned char*)(ws + (size_t)NROW * DDIM);
  float* diag = (float*)(ws + (size_t)NROW * DDIM * 2);
  float* partial = (float*)(ws + (size_t)NROW * DDIM * 2 + (size_t)NROW * 4);
  float* blocksum = (float*)(ws + (size_t)NROW * DDIM * 2 + (size_t)NROW * 4
                             + (size_t)64 * NROW * 4);

  normalize_diag<<<NROW, 256, 0, stream>>>(v1, v2, (unsigned*)z1, (unsigned*)z2,
                                           diag);
  gemm_rowsum<<<(NROW / BM) * (NROW / BN), 256, 0, stream>>>(z1, z2, partial);
  rowloss<<<NROW / 256, 256, 0, stream>>>(partial, diag, blocksum);
  finalize<<<1, 64, 0, stream>>>(blocksum, out);
}